// Round 7
// baseline (226.578 us; speedup 1.0000x reference)
//
#include <hip/hip_runtime.h>

#define LEAKY_SLOPE 0.2f

typedef float f2 __attribute__((ext_vector_type(2)));

constexpr int B_   = 16;
constexpr int N_   = 4096;
constexpr int K_   = 4096;
constexpr int IN_  = 16384;   // K + 3K
constexpr int H1_  = 1024;
constexpr int H2_  = 512;
constexpr int OUT_ = 256;

// encode tiling: 32 n-chunks x 128 points, 8 k per thread, 2 points/step
constexpr int NCH = 32;
constexpr int NPC = N_ / NCH;   // 128
constexpr int KPT = 8;
constexpr int KTB = 256 * KPT;  // 2048 -> grid.x = 2

// -------------------------------------------------------------------------
// Partial argmin over an n-chunk. Two points per step in float2 slots
// (slot x = even n, slot y = odd n) -> 3 packed fma + 2 cmp + 4 cndmask
// per 2 (k,n) pairs. e2 = pn - 2*cross (bn constant in argmin over n;
// validated r3-r6). Result: plain u64 store (mapped_e2<<32 | n) per chunk.
// grid (2,16,32) = 1024 blocks = 4/CU, 16 waves/CU.
// -------------------------------------------------------------------------
__global__ __launch_bounds__(256) void enc_partial(
    const float* __restrict__ pc, const float* __restrict__ basis,
    unsigned long long* __restrict__ part_enc)
{
#pragma clang fp contract(off)
    __shared__ f2 xs[NPC / 2], ys[NPC / 2], zs[NPC / 2], ps[NPC / 2];
    const int tid = (int)threadIdx.x;
    const int kt = blockIdx.x;
    const int b  = blockIdx.y;
    const int c  = blockIdx.z;
    const int n0 = c * NPC;

    if (tid < NPC) {
        const float* pp = pc + ((size_t)b * N_ + n0 + tid) * 3;
        float x = pp[0], y = pp[1], z = pp[2];
        ((float*)xs)[tid] = x;
        ((float*)ys)[tid] = y;
        ((float*)zs)[tid] = z;
        ((float*)ps)[tid] = (x * x + y * y) + z * z;   // numpy op order
    }
    __syncthreads();

    const int k0 = kt * KTB + tid;
    f2 nbx[KPT], nby[KPT], nbz[KPT], best[KPT];
    int bix[KPT], biy[KPT];
#pragma unroll
    for (int q = 0; q < KPT; ++q) {
        int k = k0 + q * 256;
        float vx = -2.0f * basis[k * 3 + 0];
        float vy = -2.0f * basis[k * 3 + 1];
        float vz = -2.0f * basis[k * 3 + 2];
        nbx[q] = (f2){vx, vx};
        nby[q] = (f2){vy, vy};
        nbz[q] = (f2){vz, vz};
        best[q] = (f2){3.4028235e38f, 3.4028235e38f};
        bix[q] = 0; biy[q] = 1;
    }

#pragma unroll 2
    for (int i = 0; i < NPC / 2; ++i) {
        f2 px = xs[i], py = ys[i], pz = zs[i], pw = ps[i];
#pragma unroll
        for (int q = 0; q < KPT; ++q) {
            f2 e2 = __builtin_elementwise_fma(nbx[q], px,
                     __builtin_elementwise_fma(nby[q], py,
                      __builtin_elementwise_fma(nbz[q], pz, pw)));
            if (e2.x < best[q].x) { best[q].x = e2.x; bix[q] = n0 + 2 * i; }
            if (e2.y < best[q].y) { best[q].y = e2.y; biy[q] = n0 + 2 * i + 1; }
        }
    }

#pragma unroll
    for (int q = 0; q < KPT; ++q) {
        float bb; int ii;
        // slot fold: strict <; on exact tie prefer even slot (lower n)
        if (best[q].y < best[q].x) { bb = best[q].y; ii = biy[q]; }
        else                       { bb = best[q].x; ii = bix[q]; }
        unsigned u = __float_as_uint(bb);
        u = (u & 0x80000000u) ? ~u : (u | 0x80000000u);   // monotone map
        unsigned long long v = ((unsigned long long)u << 32) | (unsigned)ii;
        part_enc[(size_t)c * (B_ * K_) + b * K_ + (k0 + q * 256)] = v;
    }
}

// -------------------------------------------------------------------------
// Fold 32 chunk keys (u64 compare = lexicographic (e2, n): equal e2 ->
// lower n wins = numpy first-min), gather nearest point, write bps row.
// -------------------------------------------------------------------------
__global__ __launch_bounds__(256) void enc_finish(
    const float* __restrict__ pc, const float* __restrict__ basis,
    const unsigned long long* __restrict__ part_enc,
    float* __restrict__ bps_out)
{
#pragma clang fp contract(off)
    const int t = blockIdx.x * 256 + (int)threadIdx.x;   // 0 .. B*K-1
    const int b = t >> 12;
    const int k = t & (K_ - 1);

    unsigned long long bestk = part_enc[t];
#pragma unroll 8
    for (int c = 1; c < NCH; ++c) {
        unsigned long long v = part_enc[(size_t)c * (B_ * K_) + t];
        if (v < bestk) bestk = v;
    }
    const int bi = (int)(unsigned)(bestk & 0xffffffffull);

    const float* p = pc + ((size_t)b * N_ + bi) * 3;
    float dx = p[0] - basis[k * 3 + 0];
    float dy = p[1] - basis[k * 3 + 1];
    float dz = p[2] - basis[k * 3 + 2];
    float dist = sqrtf((dx * dx + dy * dy) + dz * dz);

    float* row = bps_out + (size_t)b * IN_;
    row[k]              = dist;
    row[K_ + 3 * k + 0] = dx;
    row[K_ + 3 * k + 1] = dy;
    row[K_ + 3 * k + 2] = dz;
}

// -------------------------------------------------------------------------
// L1 GEMM: 4 waves/block; wave w -> batches 4w..4w+3 as 4 scalar streams
// (wave-uniform -> s_load); lane -> 4 cols (float4 W load, 1KB/wave).
// grid (4 colblocks, 128 k-chunks) = 512 blocks.
// partial: [chunk][batch(16)][H1]
// -------------------------------------------------------------------------
template<int ILEN, int NCOLS>
__global__ __launch_bounds__(256) void gemm1(
    const float* __restrict__ A, const float* __restrict__ W,
    float* __restrict__ part)
{
    const int lane = (int)threadIdx.x & 63;
    const int wg   = __builtin_amdgcn_readfirstlane((int)threadIdx.x >> 6);
    const int j0   = blockIdx.x * 256 + lane * 4;
    const int i0   = blockIdx.y * ILEN;

    const float* A0 = A + (size_t)(4 * wg + 0) * IN_ + i0;
    const float* A1 = A + (size_t)(4 * wg + 1) * IN_ + i0;
    const float* A2 = A + (size_t)(4 * wg + 2) * IN_ + i0;
    const float* A3 = A + (size_t)(4 * wg + 3) * IN_ + i0;

    float4 acc0 = {0,0,0,0}, acc1 = {0,0,0,0}, acc2 = {0,0,0,0}, acc3 = {0,0,0,0};

#pragma unroll 8
    for (int i = 0; i < ILEN; ++i) {
        float4 wv = *(const float4*)(W + (size_t)(i0 + i) * NCOLS + j0);
        float a0 = A0[i], a1 = A1[i], a2 = A2[i], a3 = A3[i];
        acc0.x = __builtin_fmaf(a0, wv.x, acc0.x);
        acc0.y = __builtin_fmaf(a0, wv.y, acc0.y);
        acc0.z = __builtin_fmaf(a0, wv.z, acc0.z);
        acc0.w = __builtin_fmaf(a0, wv.w, acc0.w);
        acc1.x = __builtin_fmaf(a1, wv.x, acc1.x);
        acc1.y = __builtin_fmaf(a1, wv.y, acc1.y);
        acc1.z = __builtin_fmaf(a1, wv.z, acc1.z);
        acc1.w = __builtin_fmaf(a1, wv.w, acc1.w);
        acc2.x = __builtin_fmaf(a2, wv.x, acc2.x);
        acc2.y = __builtin_fmaf(a2, wv.y, acc2.y);
        acc2.z = __builtin_fmaf(a2, wv.z, acc2.z);
        acc2.w = __builtin_fmaf(a2, wv.w, acc2.w);
        acc3.x = __builtin_fmaf(a3, wv.x, acc3.x);
        acc3.y = __builtin_fmaf(a3, wv.y, acc3.y);
        acc3.z = __builtin_fmaf(a3, wv.z, acc3.z);
        acc3.w = __builtin_fmaf(a3, wv.w, acc3.w);
    }

    float* base = part + (size_t)blockIdx.y * 16 * NCOLS;
    *(float4*)(base + (size_t)(4 * wg + 0) * NCOLS + j0) = acc0;
    *(float4*)(base + (size_t)(4 * wg + 1) * NCOLS + j0) = acc1;
    *(float4*)(base + (size_t)(4 * wg + 2) * NCOLS + j0) = acc2;
    *(float4*)(base + (size_t)(4 * wg + 3) * NCOLS + j0) = acc3;
}

// -------------------------------------------------------------------------
// Reduce nchunks chunk-partials + bias + leaky -> h1T[col][16]
// -------------------------------------------------------------------------
__global__ __launch_bounds__(256) void reduce_act1(
    const float* __restrict__ part, const float* __restrict__ bias,
    float* __restrict__ outT, int nchunks)
{
    const int p = blockIdx.x * 256 + (int)threadIdx.x;   // b*H1 + col
    float s = 0.0f;
#pragma unroll 8
    for (int c = 0; c < nchunks; ++c) s += part[(size_t)c * (16 * H1_) + p];
    const int col = p & (H1_ - 1);
    const int b   = p >> 10;
    s += bias[col];
    s = fmaxf(s, LEAKY_SLOPE * s);
    outT[(size_t)col * 16 + b] = s;
}

// -------------------------------------------------------------------------
// Small fused GEMM (L2/L3): one dispatch, full K. 512 threads = 8 waves;
// wave w -> k-slice; lane -> one column; 16 batch accs; LDS cross-wave
// reduce; bias (+leaky) inline.  AT layout [i][16].
// -------------------------------------------------------------------------
template<int KDIM, int NCOLS>
__global__ __launch_bounds__(512) void gemm_small(
    const float* __restrict__ AT, const float* __restrict__ W,
    const float* __restrict__ bias,
    float* __restrict__ outT, float* __restrict__ out_rm)
{
    __shared__ float red[8][64][17];
    const int lane = (int)threadIdx.x & 63;
    const int w    = __builtin_amdgcn_readfirstlane((int)threadIdx.x >> 6);
    const int j    = blockIdx.x * 64 + lane;
    constexpr int KQ = KDIM / 8;
    const int i0 = w * KQ;

    float acc[16];
#pragma unroll
    for (int r = 0; r < 16; ++r) acc[r] = 0.0f;

#pragma unroll 4
    for (int i = i0; i < i0 + KQ; ++i) {
        float wv = W[(size_t)i * NCOLS + j];
        const float4* Ar = (const float4*)(AT + (size_t)i * 16);
        float4 q0 = Ar[0], q1 = Ar[1], q2 = Ar[2], q3 = Ar[3];
        acc[0]  = __builtin_fmaf(q0.x, wv, acc[0]);
        acc[1]  = __builtin_fmaf(q0.y, wv, acc[1]);
        acc[2]  = __builtin_fmaf(q0.z, wv, acc[2]);
        acc[3]  = __builtin_fmaf(q0.w, wv, acc[3]);
        acc[4]  = __builtin_fmaf(q1.x, wv, acc[4]);
        acc[5]  = __builtin_fmaf(q1.y, wv, acc[5]);
        acc[6]  = __builtin_fmaf(q1.z, wv, acc[6]);
        acc[7]  = __builtin_fmaf(q1.w, wv, acc[7]);
        acc[8]  = __builtin_fmaf(q2.x, wv, acc[8]);
        acc[9]  = __builtin_fmaf(q2.y, wv, acc[9]);
        acc[10] = __builtin_fmaf(q2.z, wv, acc[10]);
        acc[11] = __builtin_fmaf(q2.w, wv, acc[11]);
        acc[12] = __builtin_fmaf(q3.x, wv, acc[12]);
        acc[13] = __builtin_fmaf(q3.y, wv, acc[13]);
        acc[14] = __builtin_fmaf(q3.z, wv, acc[14]);
        acc[15] = __builtin_fmaf(q3.w, wv, acc[15]);
    }

#pragma unroll
    for (int r = 0; r < 16; ++r) red[w][lane][r] = acc[r];
    __syncthreads();

#pragma unroll
    for (int q = 0; q < 2; ++q) {
        int p  = (int)threadIdx.x * 2 + q;   // col_local*16 + batch
        int cl = p >> 4;
        int bt = p & 15;
        float s = bias[blockIdx.x * 64 + cl];
#pragma unroll
        for (int ww = 0; ww < 8; ++ww) s += red[ww][cl][bt];
        if (outT) {
            s = fmaxf(s, LEAKY_SLOPE * s);
            outT[((size_t)blockIdx.x * 64 + cl) * 16 + bt] = s;
        }
        if (out_rm) {
            out_rm[(size_t)bt * NCOLS + blockIdx.x * 64 + cl] = s;
        }
    }
}

// -------------------------------------------------------------------------
extern "C" void kernel_launch(void* const* d_in, const int* in_sizes, int n_in,
                              void* d_out, int out_size, void* d_ws, size_t ws_size,
                              hipStream_t stream)
{
    const float* pc    = (const float*)d_in[0];
    const float* basis = (const float*)d_in[1];
    const float* W1    = (const float*)d_in[2];
    const float* b1    = (const float*)d_in[3];
    const float* W2    = (const float*)d_in[4];
    const float* b2    = (const float*)d_in[5];
    const float* W3    = (const float*)d_in[6];
    const float* b3    = (const float*)d_in[7];

    float* out   = (float*)d_out;
    float* gfeat = out;                 // [16][256]
    float* bps   = out + B_ * OUT_;     // [16][16384]

    char* ws = (char*)d_ws;
    unsigned long long* part_enc = (unsigned long long*)ws;      // 16MB
    float* partial = (float*)(ws + (size_t)16 * 1024 * 1024);    // 8MB
    float* h1T     = (float*)(ws + (size_t)24 * 1024 * 1024);    // 64KB
    float* h2T     = (float*)(ws + (size_t)24 * 1024 * 1024 + 64 * 1024); // 32KB

    // 1) partial argmin, plain per-chunk u64 keys (no memset, no atomics)
    enc_partial<<<dim3(K_ / KTB, B_, NCH), 256, 0, stream>>>(pc, basis, part_enc);
    // 2) fold chunks + gather + write bps feature
    enc_finish<<<(B_ * K_) / 256, 256, 0, stream>>>(pc, basis, part_enc, bps);
    // 3) L1 GEMM [16,16384]@[16384,1024]; 4 colblocks x 128 chunks
    gemm1<128, H1_><<<dim3(4, 128), 256, 0, stream>>>(bps, W1, partial);
    // 4) reduce + bias + leaky -> h1T
    reduce_act1<<<(H1_ * 16) / 256, 256, 0, stream>>>(partial, b1, h1T, 128);
    // 5) L2 fused [16,1024]@[1024,512]
    gemm_small<1024, H2_><<<8, 512, 0, stream>>>(h1T, W2, b2, h2T, nullptr);
    // 6) L3 fused [16,512]@[512,256] -> final output
    gemm_small<512, OUT_><<<4, 512, 0, stream>>>(h2T, W3, b3, nullptr, gfeat);
}

// Round 8
// 213.287 us; speedup vs baseline: 1.0623x; 1.0623x over previous
//
#include <hip/hip_runtime.h>

#define LEAKY_SLOPE 0.2f

constexpr int B_   = 16;
constexpr int N_   = 4096;
constexpr int K_   = 4096;
constexpr int IN_  = 16384;   // K + 3K
constexpr int H1_  = 1024;
constexpr int H2_  = 512;
constexpr int OUT_ = 256;

// encode tiling: 32 n-chunks x 128 points (2KB LDS), 8 k per thread
constexpr int NCH = 32;
constexpr int NPC = N_ / NCH;   // 128
constexpr int KPT = 8;
constexpr int KTB = 256 * KPT;  // 2048 k per block -> grid.x = 2

// -------------------------------------------------------------------------
// Partial argmin over an n-chunk, folded via u64 atomicMin on
// (orderable_e2_bits << 32 | n).  e2 = pn - 2*cross (bn constant in the
// argmin over n; validated r3-r7).  6 VALU ops per (k,n) pair; one
// ds_read_b128 feeds 8 k's.  grid = (2,16,32) = 1024 blocks, 16 waves/CU.
// r6-exact scalar body (r7 f2-packing regressed: +13us, VGPR 64, VALU 67%).
// -------------------------------------------------------------------------
__global__ __launch_bounds__(256) void enc_partial(
    const float* __restrict__ pc, const float* __restrict__ basis,
    unsigned long long* __restrict__ packed)
{
#pragma clang fp contract(off)
    __shared__ float4 pts[NPC];
    const int kt = blockIdx.x;
    const int b  = blockIdx.y;
    const int c  = blockIdx.z;
    const int n0 = c * NPC;

    if (threadIdx.x < NPC) {
        const float* pp = pc + ((size_t)b * N_ + n0 + threadIdx.x) * 3;
        float x = pp[0], y = pp[1], z = pp[2];
        pts[threadIdx.x] = make_float4(x, y, z, (x * x + y * y) + z * z);
    }
    __syncthreads();

    const int k0 = kt * KTB + (int)threadIdx.x;
    float nbx[KPT], nby[KPT], nbz[KPT], best[KPT];
    int   bi[KPT];
#pragma unroll
    for (int q = 0; q < KPT; ++q) {
        int k = k0 + q * 256;
        nbx[q] = -2.0f * basis[k * 3 + 0];
        nby[q] = -2.0f * basis[k * 3 + 1];
        nbz[q] = -2.0f * basis[k * 3 + 2];
        best[q] = 3.4028235e38f;
        bi[q] = 0;
    }

#pragma unroll 2
    for (int n = 0; n < NPC; ++n) {
        float4 p = pts[n];
#pragma unroll
        for (int q = 0; q < KPT; ++q) {
            float e2 = __builtin_fmaf(nbx[q], p.x,
                        __builtin_fmaf(nby[q], p.y,
                         __builtin_fmaf(nbz[q], p.z, p.w)));
            if (e2 < best[q]) { best[q] = e2; bi[q] = n0 + n; }  // strict <
        }
    }

#pragma unroll
    for (int q = 0; q < KPT; ++q) {
        unsigned u = __float_as_uint(best[q]);
        u = (u & 0x80000000u) ? ~u : (u | 0x80000000u);   // monotone map
        unsigned long long v = ((unsigned long long)u << 32) | (unsigned)bi[q];
        atomicMin(&packed[(size_t)b * K_ + (k0 + q * 256)], v);
    }
}

// -------------------------------------------------------------------------
// Unpack argmin index, gather nearest point, write bps feature row.
// -------------------------------------------------------------------------
__global__ __launch_bounds__(256) void enc_finish(
    const float* __restrict__ pc, const float* __restrict__ basis,
    const unsigned long long* __restrict__ packed,
    float* __restrict__ bps_out)
{
#pragma clang fp contract(off)
    const int t = blockIdx.x * 256 + (int)threadIdx.x;   // 0 .. B*K-1
    const int b = t >> 12;
    const int k = t & (K_ - 1);

    const int bi = (int)(unsigned)(packed[t] & 0xffffffffull);

    const float* p = pc + ((size_t)b * N_ + bi) * 3;
    float dx = p[0] - basis[k * 3 + 0];
    float dy = p[1] - basis[k * 3 + 1];
    float dz = p[2] - basis[k * 3 + 2];
    float dist = sqrtf((dx * dx + dy * dy) + dz * dz);

    float* row = bps_out + (size_t)b * IN_;
    row[k]              = dist;
    row[K_ + 3 * k + 0] = dx;
    row[K_ + 3 * k + 1] = dy;
    row[K_ + 3 * k + 2] = dz;
}

// -------------------------------------------------------------------------
// L1 GEMM: 4 waves/block; wave w -> batches 4w..4w+3 as 4 scalar streams
// from bps rows (wave-uniform -> s_load); lane -> 4 cols (float4 W load,
// 1KB/wave = the measured-peak streaming width).
// grid (4 colblocks, 128 k-chunks) = 512 blocks.  partial: [chunk][16][H1]
// -------------------------------------------------------------------------
template<int ILEN, int NCOLS>
__global__ __launch_bounds__(256) void gemm1(
    const float* __restrict__ A, const float* __restrict__ W,
    float* __restrict__ part)
{
    const int lane = (int)threadIdx.x & 63;
    const int wg   = __builtin_amdgcn_readfirstlane((int)threadIdx.x >> 6);
    const int j0   = blockIdx.x * 256 + lane * 4;
    const int i0   = blockIdx.y * ILEN;

    const float* A0 = A + (size_t)(4 * wg + 0) * IN_ + i0;
    const float* A1 = A + (size_t)(4 * wg + 1) * IN_ + i0;
    const float* A2 = A + (size_t)(4 * wg + 2) * IN_ + i0;
    const float* A3 = A + (size_t)(4 * wg + 3) * IN_ + i0;

    float4 acc0 = {0,0,0,0}, acc1 = {0,0,0,0}, acc2 = {0,0,0,0}, acc3 = {0,0,0,0};

#pragma unroll 8
    for (int i = 0; i < ILEN; ++i) {
        float4 wv = *(const float4*)(W + (size_t)(i0 + i) * NCOLS + j0);
        float a0 = A0[i], a1 = A1[i], a2 = A2[i], a3 = A3[i];
        acc0.x = __builtin_fmaf(a0, wv.x, acc0.x);
        acc0.y = __builtin_fmaf(a0, wv.y, acc0.y);
        acc0.z = __builtin_fmaf(a0, wv.z, acc0.z);
        acc0.w = __builtin_fmaf(a0, wv.w, acc0.w);
        acc1.x = __builtin_fmaf(a1, wv.x, acc1.x);
        acc1.y = __builtin_fmaf(a1, wv.y, acc1.y);
        acc1.z = __builtin_fmaf(a1, wv.z, acc1.z);
        acc1.w = __builtin_fmaf(a1, wv.w, acc1.w);
        acc2.x = __builtin_fmaf(a2, wv.x, acc2.x);
        acc2.y = __builtin_fmaf(a2, wv.y, acc2.y);
        acc2.z = __builtin_fmaf(a2, wv.z, acc2.z);
        acc2.w = __builtin_fmaf(a2, wv.w, acc2.w);
        acc3.x = __builtin_fmaf(a3, wv.x, acc3.x);
        acc3.y = __builtin_fmaf(a3, wv.y, acc3.y);
        acc3.z = __builtin_fmaf(a3, wv.z, acc3.z);
        acc3.w = __builtin_fmaf(a3, wv.w, acc3.w);
    }

    float* base = part + (size_t)blockIdx.y * 16 * NCOLS;
    *(float4*)(base + (size_t)(4 * wg + 0) * NCOLS + j0) = acc0;
    *(float4*)(base + (size_t)(4 * wg + 1) * NCOLS + j0) = acc1;
    *(float4*)(base + (size_t)(4 * wg + 2) * NCOLS + j0) = acc2;
    *(float4*)(base + (size_t)(4 * wg + 3) * NCOLS + j0) = acc3;
}

// -------------------------------------------------------------------------
// Reduce nchunks chunk-partials + bias + leaky -> h1T[col][16]
// -------------------------------------------------------------------------
__global__ __launch_bounds__(256) void reduce_act1(
    const float* __restrict__ part, const float* __restrict__ bias,
    float* __restrict__ outT, int nchunks)
{
    const int p = blockIdx.x * 256 + (int)threadIdx.x;   // b*H1 + col
    float s = 0.0f;
#pragma unroll 8
    for (int c = 0; c < nchunks; ++c) s += part[(size_t)c * (16 * H1_) + p];
    const int col = p & (H1_ - 1);
    const int b   = p >> 10;
    s += bias[col];
    s = fmaxf(s, LEAKY_SLOPE * s);
    outT[(size_t)col * 16 + b] = s;
}

// -------------------------------------------------------------------------
// Small fused GEMM (L2/L3): one dispatch, full K. 512 threads = 8 waves;
// wave w -> k-slice; lane -> one column; 16 batch accs; LDS cross-wave
// reduce; bias (+leaky) inline.  AT layout [i][16].
// -------------------------------------------------------------------------
template<int KDIM, int NCOLS>
__global__ __launch_bounds__(512) void gemm_small(
    const float* __restrict__ AT, const float* __restrict__ W,
    const float* __restrict__ bias,
    float* __restrict__ outT, float* __restrict__ out_rm)
{
    __shared__ float red[8][64][17];
    const int lane = (int)threadIdx.x & 63;
    const int w    = __builtin_amdgcn_readfirstlane((int)threadIdx.x >> 6);
    const int j    = blockIdx.x * 64 + lane;
    constexpr int KQ = KDIM / 8;
    const int i0 = w * KQ;

    float acc[16];
#pragma unroll
    for (int r = 0; r < 16; ++r) acc[r] = 0.0f;

#pragma unroll 4
    for (int i = i0; i < i0 + KQ; ++i) {
        float wv = W[(size_t)i * NCOLS + j];
        const float4* Ar = (const float4*)(AT + (size_t)i * 16);
        float4 q0 = Ar[0], q1 = Ar[1], q2 = Ar[2], q3 = Ar[3];
        acc[0]  = __builtin_fmaf(q0.x, wv, acc[0]);
        acc[1]  = __builtin_fmaf(q0.y, wv, acc[1]);
        acc[2]  = __builtin_fmaf(q0.z, wv, acc[2]);
        acc[3]  = __builtin_fmaf(q0.w, wv, acc[3]);
        acc[4]  = __builtin_fmaf(q1.x, wv, acc[4]);
        acc[5]  = __builtin_fmaf(q1.y, wv, acc[5]);
        acc[6]  = __builtin_fmaf(q1.z, wv, acc[6]);
        acc[7]  = __builtin_fmaf(q1.w, wv, acc[7]);
        acc[8]  = __builtin_fmaf(q2.x, wv, acc[8]);
        acc[9]  = __builtin_fmaf(q2.y, wv, acc[9]);
        acc[10] = __builtin_fmaf(q2.z, wv, acc[10]);
        acc[11] = __builtin_fmaf(q2.w, wv, acc[11]);
        acc[12] = __builtin_fmaf(q3.x, wv, acc[12]);
        acc[13] = __builtin_fmaf(q3.y, wv, acc[13]);
        acc[14] = __builtin_fmaf(q3.z, wv, acc[14]);
        acc[15] = __builtin_fmaf(q3.w, wv, acc[15]);
    }

#pragma unroll
    for (int r = 0; r < 16; ++r) red[w][lane][r] = acc[r];
    __syncthreads();

#pragma unroll
    for (int q = 0; q < 2; ++q) {
        int p  = (int)threadIdx.x * 2 + q;   // col_local*16 + batch
        int cl = p >> 4;
        int bt = p & 15;
        float s = bias[blockIdx.x * 64 + cl];
#pragma unroll
        for (int ww = 0; ww < 8; ++ww) s += red[ww][cl][bt];
        if (outT) {
            s = fmaxf(s, LEAKY_SLOPE * s);
            outT[((size_t)blockIdx.x * 64 + cl) * 16 + bt] = s;
        }
        if (out_rm) {
            out_rm[(size_t)bt * NCOLS + blockIdx.x * 64 + cl] = s;
        }
    }
}

// -------------------------------------------------------------------------
extern "C" void kernel_launch(void* const* d_in, const int* in_sizes, int n_in,
                              void* d_out, int out_size, void* d_ws, size_t ws_size,
                              hipStream_t stream)
{
    const float* pc    = (const float*)d_in[0];
    const float* basis = (const float*)d_in[1];
    const float* W1    = (const float*)d_in[2];
    const float* b1    = (const float*)d_in[3];
    const float* W2    = (const float*)d_in[4];
    const float* b2    = (const float*)d_in[5];
    const float* W3    = (const float*)d_in[6];
    const float* b3    = (const float*)d_in[7];

    float* out   = (float*)d_out;
    float* gfeat = out;                 // [16][256]
    float* bps   = out + B_ * OUT_;     // [16][16384]

    char* ws = (char*)d_ws;
    unsigned long long* packed = (unsigned long long*)ws;        // 512KB
    float* partial = (float*)(ws + (size_t)1024 * 1024);         // 8MB
    float* h1T     = (float*)(ws + (size_t)10 * 1024 * 1024);    // 64KB
    float* h2T     = (float*)(ws + (size_t)10 * 1024 * 1024 + 64 * 1024); // 32KB

    // 1) init packed keys to +inf
    hipMemsetAsync(packed, 0xFF, (size_t)B_ * K_ * 8, stream);
    // 2) partial argmin, atomic fold (1024 blocks, 16 waves/CU)
    enc_partial<<<dim3(K_ / KTB, B_, NCH), 256, 0, stream>>>(pc, basis, packed);
    // 3) gather + write bps feature
    enc_finish<<<(B_ * K_) / 256, 256, 0, stream>>>(pc, basis, packed, bps);
    // 4) L1 GEMM [16,16384]@[16384,1024]; 4 colblocks x 128 chunks
    gemm1<128, H1_><<<dim3(4, 128), 256, 0, stream>>>(bps, W1, partial);
    // 5) reduce + bias + leaky -> h1T
    reduce_act1<<<(H1_ * 16) / 256, 256, 0, stream>>>(partial, b1, h1T, 128);
    // 6) L2 fused [16,1024]@[1024,512]
    gemm_small<1024, H2_><<<8, 512, 0, stream>>>(h1T, W2, b2, h2T, nullptr);
    // 7) L3 fused [16,512]@[512,256] -> final output
    gemm_small<512, OUT_><<<4, 512, 0, stream>>>(h2T, W3, b3, nullptr, gfeat);
}